// Round 2
// baseline (712.466 us; speedup 1.0000x reference)
//
#include <hip/hip_runtime.h>
#include <math.h>

#define B_     16
#define C_     512
#define T_     8192
#define T4_    (T_/4)       // 2048
#define TILE_T 64           // t values per block
#define SLOTS  16           // float4 slots per tile (TILE_T/4)
#define TILES  (T_/TILE_T)  // 128 tiles per b
#define NBLK   (B_*TILES)   // 2048 blocks
#define CPT    32           // channels per thread (C_/16)

// Decoupled-lookback record, one per (b, tile). 48 bytes.
struct Rec {
    double agg_s, agg_ss;   // this tile's aggregate (sum over its 64 t)
    double inc_s, inc_ss;   // inclusive prefix through this tile
    int    status;          // 0 = none, 1 = aggregate ready, 2 = inclusive ready
    int    pad[3];
};

__global__ void init_recs(Rec* recs) {
    int i = blockIdx.x * blockDim.x + threadIdx.x;
    if (i < NBLK) recs[i].status = 0;
}

__global__ __launch_bounds__(256, 2)
void fused_kernel(const float* __restrict__ x,
                  const float* __restrict__ gains,
                  const float* __restrict__ bias,
                  float* __restrict__ out,
                  Rec* __restrict__ recs) {
    const int bid  = blockIdx.x;
    const int b    = bid & (B_ - 1);   // b-major interleave: parallel chains,
    const int tile = bid >> 4;         // resident set always holds predecessors
    const int tid  = threadIdx.x;
    const int slot = tid & 15;         // which float4 of t within the tile
    const int c0   = tid >> 4;         // 0..15 channel group

    __shared__ float4 rs[16][SLOTS];   // [c0][slot] partial sums
    __shared__ float4 rss[16][SLOTS];
    __shared__ double pre_s[TILE_T], pre_ss[TILE_T];  // tile-local inclusive prefix
    __shared__ float  mean_l[TILE_T], rstd_l[TILE_T];
    __shared__ double sh_exc_s, sh_exc_ss;
    __shared__ float  sh_g[C_], sh_b[C_];

    // stage gains/bias (512 each) into LDS
    sh_g[tid]       = gains[tid];
    sh_g[tid + 256] = gains[tid + 256];
    sh_b[tid]       = bias[tid];
    sh_b[tid + 256] = bias[tid + 256];

    // ---- load this block's x slab into registers (read x exactly once) ----
    // address: x[b, c0 + 16*j, tile*64 + slot*4 .. +3], j = 0..31
    const size_t chan_stride = (size_t)16 * T4_;  // 16 channels, in float4 units
    const float4* xb = (const float4*)x
        + (size_t)(b * C_ + c0) * T4_ + (size_t)tile * SLOTS + slot;
    float4 v[CPT];
    #pragma unroll
    for (int j = 0; j < CPT; ++j)
        v[j] = xb[(size_t)j * chan_stride];

    float4 s4  = make_float4(0.f, 0.f, 0.f, 0.f);
    float4 ss4 = make_float4(0.f, 0.f, 0.f, 0.f);
    #pragma unroll
    for (int j = 0; j < CPT; ++j) {
        float4 w = v[j];
        s4.x  += w.x;     s4.y  += w.y;     s4.z  += w.z;     s4.w  += w.w;
        ss4.x += w.x*w.x; ss4.y += w.y*w.y; ss4.z += w.z*w.z; ss4.w += w.w*w.w;
    }
    rs[c0][slot]  = s4;
    rss[c0][slot] = ss4;
    __syncthreads();

    // ---- reduce the 16 channel-groups per slot ----
    if (tid < SLOTS) {
        float4 a = make_float4(0.f, 0.f, 0.f, 0.f);
        float4 q = make_float4(0.f, 0.f, 0.f, 0.f);
        for (int k = 0; k < 16; ++k) {
            float4 t1 = rs[k][tid], t2 = rss[k][tid];
            a.x += t1.x; a.y += t1.y; a.z += t1.z; a.w += t1.w;
            q.x += t2.x; q.y += t2.y; q.z += t2.z; q.w += t2.w;
        }
        rs[0][tid]  = a;   // per-slot (per-4-t) totals
        rss[0][tid] = q;
    }
    __syncthreads();

    // ---- tile-local scan (double) + decoupled lookback, thread 0 ----
    if (tid == 0) {
        const float* fs  = (const float*)&rs[0][0];   // flat [64] per-t sums
        const float* fss = (const float*)&rss[0][0];
        double run_s = 0.0, run_ss = 0.0;
        for (int t = 0; t < TILE_T; ++t) {
            run_s  += (double)fs[t];
            run_ss += (double)fss[t];
            pre_s[t]  = run_s;
            pre_ss[t] = run_ss;
        }
        Rec* my = &recs[b * TILES + tile];
        double exc_s = 0.0, exc_ss = 0.0;
        if (tile == 0) {
            my->inc_s = run_s; my->inc_ss = run_ss;
            __hip_atomic_store(&my->status, 2, __ATOMIC_RELEASE,
                               __HIP_MEMORY_SCOPE_AGENT);
        } else {
            my->agg_s = run_s; my->agg_ss = run_ss;
            __hip_atomic_store(&my->status, 1, __ATOMIC_RELEASE,
                               __HIP_MEMORY_SCOPE_AGENT);
            int look = tile - 1;
            for (;;) {
                Rec* r = &recs[b * TILES + look];
                int st;
                do {
                    st = __hip_atomic_load(&r->status, __ATOMIC_ACQUIRE,
                                           __HIP_MEMORY_SCOPE_AGENT);
                } while (st == 0);
                if (st == 2) { exc_s += r->inc_s; exc_ss += r->inc_ss; break; }
                exc_s += r->agg_s; exc_ss += r->agg_ss;
                --look;
            }
            my->inc_s = exc_s + run_s; my->inc_ss = exc_ss + run_ss;
            __hip_atomic_store(&my->status, 2, __ATOMIC_RELEASE,
                               __HIP_MEMORY_SCOPE_AGENT);
        }
        sh_exc_s = exc_s; sh_exc_ss = exc_ss;
    }
    __syncthreads();

    // ---- mean / rstd per t (double, matches-or-beats np fp32 reference) ----
    if (tid < TILE_T) {
        int tg = tile * TILE_T + tid;
        double is  = sh_exc_s  + pre_s[tid];
        double iss = sh_exc_ss + pre_ss[tid];
        double div = 512.0 * (double)(tg + 1);   // DIV_CONST * (t+1)
        double m   = is / div;
        double msq = iss / div;
        double var = msq - m * m;
        double r   = 1.0 / sqrt(var + 1e-8);     // EPS
        mean_l[tid] = (float)m;
        rstd_l[tid] = (float)r;
    }
    __syncthreads();

    // ---- normalize from registers, write out (write out exactly once) ----
    float4 m4 = ((const float4*)mean_l)[slot];
    float4 r4 = ((const float4*)rstd_l)[slot];
    float4* ob = (float4*)out
        + (size_t)(b * C_ + c0) * T4_ + (size_t)tile * SLOTS + slot;
    #pragma unroll
    for (int j = 0; j < CPT; ++j) {
        int c = c0 + 16 * j;
        float g  = sh_g[c];
        float bi = sh_b[c];
        float4 w = v[j], o;
        o.x = (w.x - m4.x) * r4.x * g + bi;
        o.y = (w.y - m4.y) * r4.y * g + bi;
        o.z = (w.z - m4.z) * r4.z * g + bi;
        o.w = (w.w - m4.w) * r4.w * g + bi;
        ob[(size_t)j * chan_stride] = o;
    }
}

extern "C" void kernel_launch(void* const* d_in, const int* in_sizes, int n_in,
                              void* d_out, int out_size, void* d_ws, size_t ws_size,
                              hipStream_t stream) {
    const float* x     = (const float*)d_in[0];
    const float* gains = (const float*)d_in[1];
    const float* bias  = (const float*)d_in[2];
    float* out = (float*)d_out;
    Rec* recs  = (Rec*)d_ws;   // 2048 * 48 B = 96 KB

    init_recs<<<NBLK / 256, 256, 0, stream>>>(recs);
    fused_kernel<<<NBLK, 256, 0, stream>>>(x, gains, bias, out, recs);
}